// Round 1
// baseline (162.409 us; speedup 1.0000x reference)
//
#include <hip/hip_runtime.h>

// GeometricAttention: B=4, N=256, FDIM=256, REL=16, H=8, D=32
// Decomposition:
//   K[b,i,j] = Kn[b,j] + rel[b,i,j] @ Wk_r          (Kn = nf@Wk_f + bk)
//   scores   = Q.Kn^T + Qr.rel^T                     (Qr = per-head Q @ Wk_r^T)
//   sum_j attn*V = attn@Vn + (attn@rel)@Wv_r         (Vn = nf@Wv_f + bv)
// Reduces 73 GFLOP naive per-edge K/V to ~1 GFLOP, all fp32 exact.

#define BB 4
#define NN 256
#define FD 256
#define RL 16
#define NH 8
#define HD 32

// ws layout (float offsets)
#define OFF_Q    0
#define OFF_KN   (BB*NN*FD)            // 262144
#define OFF_VN   (2*BB*NN*FD)          // 524288
#define OFF_QR   (3*BB*NN*FD)          // 786432
#define OFF_ATTN (OFF_QR + BB*NN*NH*RL)       // 917504
#define OFF_AREL (OFF_ATTN + BB*NH*NN*NN)     // 3014656
#define OFF_WV   (OFF_AREL + BB*NN*NH*RL)     // 3145728

// ---------------- Kernel 1: Q / Kn / Vn projections (fused, sel = blockIdx.y)
__global__ __launch_bounds__(256) void k_qkv(
    const float* __restrict__ nf,
    const float* __restrict__ Wq, const float* __restrict__ bq,
    const float* __restrict__ Wk, const float* __restrict__ bk,
    const float* __restrict__ Wv, const float* __restrict__ bv,
    float* __restrict__ ws) {
  const int ROWS = 8;
  __shared__ float lrow[ROWS * FD];
  const int row0 = blockIdx.x * ROWS;   // row in [0, B*N)
  const int sel  = blockIdx.y;          // 0=Q, 1=Kn, 2=Vn
  const float* W; const float* bias; float* outp;
  if (sel == 0)      { W = Wq; bias = bq; outp = ws + OFF_Q;  }
  else if (sel == 1) { W = Wk; bias = bk; outp = ws + OFF_KN; }
  else               { W = Wv; bias = bv; outp = ws + OFF_VN; }
  const int tid = threadIdx.x;
  #pragma unroll
  for (int t = 0; t < ROWS; ++t)
    lrow[t * FD + tid] = nf[(row0 + t) * FD + tid];
  __syncthreads();
  float acc[ROWS];
  #pragma unroll
  for (int r = 0; r < ROWS; ++r) acc[r] = 0.f;
  #pragma unroll 4
  for (int k = 0; k < FD; ++k) {
    const float w = W[k * FD + tid];   // Wk/Wv: row stride is still 256 (out dim)
    #pragma unroll
    for (int r = 0; r < ROWS; ++r) acc[r] += lrow[r * FD + k] * w;
  }
  const float bb = bias[tid];
  #pragma unroll
  for (int r = 0; r < ROWS; ++r)
    outp[(row0 + r) * FD + tid] = acc[r] + bb;
}

// ---------------- Kernel 2: Qr[b,i,h,r] = sum_d Q[b,i,h,d] * Wk[256+r, h*32+d]
__global__ __launch_bounds__(128) void k_qr(const float* __restrict__ Wk,
                                            float* __restrict__ ws) {
  const float* Q = ws + OFF_Q;
  float* Qr = ws + OFF_QR;
  const int bi = blockIdx.x;            // b*N + i
  const int tid = threadIdx.x;          // h*16 + r
  __shared__ float q[FD];
  q[tid]       = Q[bi * FD + tid];
  q[tid + 128] = Q[bi * FD + tid + 128];
  __syncthreads();
  const int h = tid >> 4, r = tid & 15;
  const float* wrow = Wk + (FD + r) * FD + h * HD;
  float a = 0.f;
  #pragma unroll
  for (int d = 0; d < HD; ++d) a += q[h * HD + d] * wrow[d];
  Qr[bi * (NH * RL) + tid] = a;
}

// ---------------- Kernel 3: scores + softmax, one block per (b,i), thread = j
__global__ __launch_bounds__(256) void k_attn(const float* __restrict__ rel,
                                              float* __restrict__ ws) {
  const float* Q  = ws + OFF_Q;
  const float* Kn = ws + OFF_KN;
  const float* Qr = ws + OFF_QR;
  float* attn = ws + OFF_ATTN;
  const int b = blockIdx.x >> 8;
  const int i = blockIdx.x & 255;
  const int j = threadIdx.x;
  const int lane = j & 63, wid = j >> 6;

  __shared__ float q[FD];
  __shared__ float qr[NH * RL];
  __shared__ float red[4][8];

  q[j] = Q[(b * NN + i) * FD + j];
  if (j < NH * RL) qr[j] = Qr[(b * NN + i) * NH * RL + j];
  __syncthreads();

  // rel row for this (b,i,j): 16 floats
  float rl[RL];
  {
    const float4* rp = (const float4*)(rel + (((size_t)(b * NN + i)) * NN + j) * RL);
    #pragma unroll
    for (int t = 0; t < 4; ++t) {
      float4 v = rp[t];
      rl[4*t+0] = v.x; rl[4*t+1] = v.y; rl[4*t+2] = v.z; rl[4*t+3] = v.w;
    }
  }

  const float scale = 0.17677669529663687f;  // 1/sqrt(32)
  float sc[NH];
  const float4* kn4 = (const float4*)(Kn + (b * NN + j) * FD);
  #pragma unroll
  for (int h = 0; h < NH; ++h) {
    float s = 0.f;
    #pragma unroll
    for (int d4 = 0; d4 < HD / 4; ++d4) {
      float4 kv = kn4[h * (HD / 4) + d4];
      s += q[h * HD + d4 * 4 + 0] * kv.x;
      s += q[h * HD + d4 * 4 + 1] * kv.y;
      s += q[h * HD + d4 * 4 + 2] * kv.z;
      s += q[h * HD + d4 * 4 + 3] * kv.w;
    }
    #pragma unroll
    for (int r = 0; r < RL; ++r) s += qr[h * RL + r] * rl[r];
    sc[h] = s * scale;
  }

  // block max per h
  float mx[NH];
  #pragma unroll
  for (int h = 0; h < NH; ++h) {
    float v = sc[h];
    #pragma unroll
    for (int off = 32; off; off >>= 1) v = fmaxf(v, __shfl_xor(v, off));
    if (lane == 0) red[wid][h] = v;
  }
  __syncthreads();
  #pragma unroll
  for (int h = 0; h < NH; ++h)
    mx[h] = fmaxf(fmaxf(red[0][h], red[1][h]), fmaxf(red[2][h], red[3][h]));
  __syncthreads();

  // exp + block sum per h
  float p[NH], sm[NH];
  #pragma unroll
  for (int h = 0; h < NH; ++h) {
    p[h] = expf(sc[h] - mx[h]);
    float v = p[h];
    #pragma unroll
    for (int off = 32; off; off >>= 1) v += __shfl_xor(v, off);
    if (lane == 0) red[wid][h] = v;
  }
  __syncthreads();
  #pragma unroll
  for (int h = 0; h < NH; ++h)
    sm[h] = red[0][h] + red[1][h] + red[2][h] + red[3][h];

  #pragma unroll
  for (int h = 0; h < NH; ++h)
    attn[(((b * NH + h) * NN) + i) * NN + j] = p[h] / sm[h];
}

// ---------------- Kernel 4: arel[b,i,h,r] = sum_j attn[b,h,i,j] * rel[b,i,j,r]
__global__ __launch_bounds__(128) void k_arel(const float* __restrict__ rel,
                                              float* __restrict__ ws) {
  const float* attn = ws + OFF_ATTN;
  float* arel = ws + OFF_AREL;
  const int b = blockIdx.x >> 8;
  const int i = blockIdx.x & 255;
  const int tid = threadIdx.x;  // h*16 + r
  __shared__ float at[NH][NN + 1];
  __shared__ float rlds[NN][RL];
  #pragma unroll
  for (int h = 0; h < NH; ++h) {
    at[h][tid]       = attn[(((b * NH + h) * NN) + i) * NN + tid];
    at[h][tid + 128] = attn[(((b * NH + h) * NN) + i) * NN + tid + 128];
  }
  {
    const float4* rp = (const float4*)(rel + ((size_t)(b * NN + i)) * NN * RL);
    float4* lp = (float4*)&rlds[0][0];
    #pragma unroll
    for (int t = 0; t < 8; ++t) lp[tid + t * 128] = rp[tid + t * 128];
  }
  __syncthreads();
  const int h = tid >> 4, r = tid & 15;
  float a = 0.f;
  #pragma unroll 4
  for (int j = 0; j < NN; ++j) a += at[h][j] * rlds[j][r];
  arel[(b * NN + i) * (NH * RL) + tid] = a;
}

// ---------------- Kernel 5: wv[b,i,c] = sum_j attn*Vn[b,j,c] + sum_r arel*Wv_r[r,c]
__global__ __launch_bounds__(256) void k_wv(const float* __restrict__ Wv,
                                            float* __restrict__ ws) {
  const float* Vn   = ws + OFF_VN;
  const float* attn = ws + OFF_ATTN;
  const float* arel = ws + OFF_AREL;
  float* wv = ws + OFF_WV;
  const int b = blockIdx.x >> 8;
  const int i = blockIdx.x & 255;
  const int c = threadIdx.x;
  const int h = c >> 5;
  __shared__ float at[NH][NN];
  __shared__ float ar[NH * RL];
  #pragma unroll
  for (int hh = 0; hh < NH; ++hh)
    at[hh][c] = attn[(((b * NH + hh) * NN) + i) * NN + c];
  if (c < NH * RL) ar[c] = arel[(b * NN + i) * (NH * RL) + c];
  __syncthreads();
  float acc = 0.f;
  #pragma unroll 4
  for (int j = 0; j < NN; ++j)
    acc += at[h][j] * Vn[(b * NN + j) * FD + c];
  #pragma unroll
  for (int r = 0; r < RL; ++r)
    acc += ar[h * RL + r] * Wv[(FD + r) * FD + c];
  wv[(b * NN + i) * FD + c] = acc;
}

// ---------------- Kernel 6: out = nf + wv @ Wo + bo
__global__ __launch_bounds__(256) void k_out(const float* __restrict__ nf,
                                             const float* __restrict__ Wo,
                                             const float* __restrict__ bo,
                                             const float* __restrict__ ws,
                                             float* __restrict__ out) {
  const int ROWS = 8;
  const float* wv = ws + OFF_WV;
  __shared__ float lrow[ROWS * FD];
  const int row0 = blockIdx.x * ROWS;
  const int tid = threadIdx.x;
  #pragma unroll
  for (int t = 0; t < ROWS; ++t)
    lrow[t * FD + tid] = wv[(row0 + t) * FD + tid];
  __syncthreads();
  float acc[ROWS];
  #pragma unroll
  for (int r = 0; r < ROWS; ++r) acc[r] = 0.f;
  #pragma unroll 4
  for (int k = 0; k < FD; ++k) {
    const float w = Wo[k * FD + tid];
    #pragma unroll
    for (int r = 0; r < ROWS; ++r) acc[r] += lrow[r * FD + k] * w;
  }
  const float bb = bo[tid];
  #pragma unroll
  for (int r = 0; r < ROWS; ++r)
    out[(row0 + r) * FD + tid] = nf[(row0 + r) * FD + tid] + acc[r] + bb;
}

extern "C" void kernel_launch(void* const* d_in, const int* in_sizes, int n_in,
                              void* d_out, int out_size, void* d_ws, size_t ws_size,
                              hipStream_t stream) {
  const float* nf  = (const float*)d_in[0];
  const float* rel = (const float*)d_in[1];
  const float* Wq  = (const float*)d_in[2];
  const float* bq  = (const float*)d_in[3];
  const float* Wk  = (const float*)d_in[4];
  const float* bk  = (const float*)d_in[5];
  const float* Wv  = (const float*)d_in[6];
  const float* bv  = (const float*)d_in[7];
  const float* Wo  = (const float*)d_in[8];
  const float* bo  = (const float*)d_in[9];
  float* out = (float*)d_out;
  float* ws  = (float*)d_ws;

  k_qkv <<<dim3(BB * NN / 8, 3), 256, 0, stream>>>(nf, Wq, bq, Wk, bk, Wv, bv, ws);
  k_qr  <<<BB * NN, 128, 0, stream>>>(Wk, ws);
  k_attn<<<BB * NN, 256, 0, stream>>>(rel, ws);
  k_arel<<<BB * NN, 128, 0, stream>>>(rel, ws);
  k_wv  <<<BB * NN, 256, 0, stream>>>(Wv, ws);
  k_out <<<BB * NN / 8, 256, 0, stream>>>(nf, Wo, bo, ws, out);
}

// Round 2
// 101.682 us; speedup vs baseline: 1.5972x; 1.5972x over previous
//
#include <hip/hip_runtime.h>

// GeometricAttention: B=4, N=256, FDIM=256, REL=16, H=8, D=32
// Decomposition (exact, fp32):
//   K[b,i,j] = Kn[b,j] + rel[b,i,j] @ Wk_r          (Kn = nf@Wk_f + bk)
//   scores   = Q.Kn^T + Qr.rel^T                     (Qr = per-head Q @ Wk_r^T)
//   sum_j attn*V = attn@Vn + (attn@rel)@Wv_r         (Vn = nf@Wv_f + bv)
// Round 2: Kn stored TRANSPOSED (KnT[b][f][j]) so the score loop is coalesced;
// qr/scores/softmax/arel/wv fused into one kernel per (b,i) — attn and rel
// never round-trip through HBM.

#define BB 4
#define NN 256
#define FD 256
#define RL 16
#define NH 8
#define HD 32

// ws layout (float offsets)
#define OFF_Q    0
#define OFF_KN   (BB*NN*FD)            // KnT: [b][f][j]
#define OFF_VN   (2*BB*NN*FD)          // Vn:  [b][j][c]
#define OFF_WV   (3*BB*NN*FD)

// ---------------- Kernel 1: Q / KnT / Vn projections (fused, sel = blockIdx.y)
__global__ __launch_bounds__(256) void k_qkv(
    const float* __restrict__ nf,
    const float* __restrict__ Wq, const float* __restrict__ bq,
    const float* __restrict__ Wk, const float* __restrict__ bk,
    const float* __restrict__ Wv, const float* __restrict__ bv,
    float* __restrict__ ws) {
  const int ROWS = 8;
  __shared__ float lrow[ROWS * FD];
  const int row0 = blockIdx.x * ROWS;   // row in [0, B*N); never straddles b
  const int sel  = blockIdx.y;          // 0=Q, 1=KnT, 2=Vn
  const float* W; const float* bias;
  if (sel == 0)      { W = Wq; bias = bq; }
  else if (sel == 1) { W = Wk; bias = bk; }
  else               { W = Wv; bias = bv; }
  const int tid = threadIdx.x;
  #pragma unroll
  for (int t = 0; t < ROWS; ++t)
    lrow[t * FD + tid] = nf[(row0 + t) * FD + tid];
  __syncthreads();
  float acc[ROWS];
  #pragma unroll
  for (int r = 0; r < ROWS; ++r) acc[r] = 0.f;
  #pragma unroll 4
  for (int k = 0; k < FD; ++k) {
    const float w = W[k * FD + tid];
    #pragma unroll
    for (int r = 0; r < ROWS; ++r) acc[r] += lrow[r * FD + k] * w;
  }
  const float bb = bias[tid];
  if (sel == 1) {
    // KnT[b][f=tid][i0+r], 8 consecutive floats per lane (32B, aligned)
    const int b2 = row0 >> 8, i0 = row0 & 255;
    float* kout = ws + OFF_KN + b2 * (FD * NN) + tid * NN + i0;
    float4 v0 = make_float4(acc[0] + bb, acc[1] + bb, acc[2] + bb, acc[3] + bb);
    float4 v1 = make_float4(acc[4] + bb, acc[5] + bb, acc[6] + bb, acc[7] + bb);
    ((float4*)kout)[0] = v0;
    ((float4*)kout)[1] = v1;
  } else {
    float* outp = ws + (sel == 0 ? OFF_Q : OFF_VN);
    #pragma unroll
    for (int r = 0; r < ROWS; ++r)
      outp[(row0 + r) * FD + tid] = acc[r] + bb;
  }
}

// ---------------- Kernel 2 (fused): qr + scores + softmax + arel + wv
// one block per (b,i); thread = j for scores, = c for wv
__global__ __launch_bounds__(256, 4) void k_attn2(
    const float* __restrict__ rel,
    const float* __restrict__ Wk,
    const float* __restrict__ Wv,
    float* __restrict__ ws) {
  const float* Q   = ws + OFF_Q;
  const float* KnT = ws + OFF_KN;
  const float* Vn  = ws + OFF_VN;
  float* wv = ws + OFF_WV;

  const int b = blockIdx.x >> 8;
  const int i = blockIdx.x & 255;
  const int tid = threadIdx.x;
  const int lane = tid & 63, wid = tid >> 6;

  __shared__ float q[FD];
  __shared__ float qr[NH * RL];
  __shared__ float rlds[NN * 17];   // rel rows, padded stride 17
  __shared__ float at[NH][NN];      // scores -> attn probs
  __shared__ float ar[NH * RL];     // arel
  __shared__ float red[4][NH];

  q[tid] = Q[(b * NN + i) * FD + tid];
  {
    const float* rp = rel + ((size_t)(b * NN + i)) * (NN * RL);
    #pragma unroll
    for (int t = 0; t < 16; ++t) {
      int idx = tid + t * 256;     // 4096 contiguous floats, coalesced
      rlds[(idx >> 4) * 17 + (idx & 15)] = rp[idx];
    }
  }
  __syncthreads();

  // qr[h][r] = sum_d q[h*32+d] * Wk[256+r][h*32+d]  (first 128 threads)
  if (tid < NH * RL) {
    const int h = tid >> 4, r = tid & 15;
    const float* wrow = Wk + (FD + r) * FD + h * HD;
    float a = 0.f;
    #pragma unroll
    for (int d = 0; d < HD; ++d) a += q[h * HD + d] * wrow[d];
    qr[tid] = a;
  }

  // own rel row -> regs (conflict-free via pad-17)
  float rl[RL];
  #pragma unroll
  for (int r = 0; r < RL; ++r) rl[r] = rlds[tid * 17 + r];
  __syncthreads();   // qr visible

  // ---- scores: sc[h] = q . KnT[:,j] (coalesced) + qr[h,:] . rel[i,j,:]
  const float scale = 0.17677669529663687f;  // 1/sqrt(32)
  {
    const float* knp = KnT + b * (FD * NN) + tid;
    const float4* q4  = (const float4*)q;
    const float4* qr4 = (const float4*)qr;
    #pragma unroll 2
    for (int h = 0; h < NH; ++h) {
      float s = 0.f;
      #pragma unroll
      for (int d4 = 0; d4 < 8; ++d4) {
        float4 qv = q4[h * 8 + d4];
        const float* kp = knp + (h * HD + d4 * 4) * NN;
        s += qv.x * kp[0] + qv.y * kp[NN] + qv.z * kp[2 * NN] + qv.w * kp[3 * NN];
      }
      float sr = 0.f;
      #pragma unroll
      for (int r4 = 0; r4 < 4; ++r4) {
        float4 qv = qr4[h * 4 + r4];
        sr += qv.x * rl[r4 * 4 + 0] + qv.y * rl[r4 * 4 + 1]
            + qv.z * rl[r4 * 4 + 2] + qv.w * rl[r4 * 4 + 3];
      }
      at[h][tid] = (s + sr) * scale;
    }
  }

  // ---- softmax over j (own value from own LDS slot; no barrier needed yet)
  float p[NH], mx[NH], sm[NH];
  #pragma unroll
  for (int h = 0; h < NH; ++h) {
    float v = at[h][tid];
    p[h] = v;  // raw score for now
    #pragma unroll
    for (int off = 32; off; off >>= 1) v = fmaxf(v, __shfl_xor(v, off));
    if (lane == 0) red[wid][h] = v;
  }
  __syncthreads();
  #pragma unroll
  for (int h = 0; h < NH; ++h)
    mx[h] = fmaxf(fmaxf(red[0][h], red[1][h]), fmaxf(red[2][h], red[3][h]));
  __syncthreads();
  #pragma unroll
  for (int h = 0; h < NH; ++h) {
    p[h] = expf(p[h] - mx[h]);
    float v = p[h];
    #pragma unroll
    for (int off = 32; off; off >>= 1) v += __shfl_xor(v, off);
    if (lane == 0) red[wid][h] = v;
  }
  __syncthreads();
  #pragma unroll
  for (int h = 0; h < NH; ++h) {
    sm[h] = red[0][h] + red[1][h] + red[2][h] + red[3][h];
    at[h][tid] = p[h] / sm[h];   // normalized prob back to LDS
  }
  __syncthreads();

  // ---- arel[h][r] = sum_j at[h][j] * rel[j][r]   (first 128 threads)
  if (tid < NH * RL) {
    const int h = tid >> 4, r = tid & 15;
    float a = 0.f;
    #pragma unroll 4
    for (int j = 0; j < NN; ++j) a += at[h][j] * rlds[j * 17 + r];
    ar[tid] = a;
  }
  __syncthreads();

  // ---- wv[c] = sum_j at[h][j]*Vn[b][j][c] + sum_r ar[h][r]*Wv_r[r][c]
  {
    const int c = tid, h = c >> 5;
    const float* vp = Vn + b * (NN * FD) + c;
    float acc = 0.f;
    #pragma unroll 4
    for (int j = 0; j < NN; ++j)
      acc += at[h][j] * vp[j * FD];
    #pragma unroll
    for (int r = 0; r < RL; ++r)
      acc += ar[h * RL + r] * Wv[(FD + r) * FD + c];
    wv[(b * NN + i) * FD + c] = acc;
  }
}

// ---------------- Kernel 3: out = nf + wv @ Wo + bo
__global__ __launch_bounds__(256) void k_out(const float* __restrict__ nf,
                                             const float* __restrict__ Wo,
                                             const float* __restrict__ bo,
                                             const float* __restrict__ ws,
                                             float* __restrict__ out) {
  const int ROWS = 8;
  const float* wv = ws + OFF_WV;
  __shared__ float lrow[ROWS * FD];
  const int row0 = blockIdx.x * ROWS;
  const int tid = threadIdx.x;
  #pragma unroll
  for (int t = 0; t < ROWS; ++t)
    lrow[t * FD + tid] = wv[(row0 + t) * FD + tid];
  __syncthreads();
  float acc[ROWS];
  #pragma unroll
  for (int r = 0; r < ROWS; ++r) acc[r] = 0.f;
  #pragma unroll 4
  for (int k = 0; k < FD; ++k) {
    const float w = Wo[k * FD + tid];
    #pragma unroll
    for (int r = 0; r < ROWS; ++r) acc[r] += lrow[r * FD + k] * w;
  }
  const float bb = bo[tid];
  #pragma unroll
  for (int r = 0; r < ROWS; ++r)
    out[(row0 + r) * FD + tid] = nf[(row0 + r) * FD + tid] + acc[r] + bb;
}

extern "C" void kernel_launch(void* const* d_in, const int* in_sizes, int n_in,
                              void* d_out, int out_size, void* d_ws, size_t ws_size,
                              hipStream_t stream) {
  const float* nf  = (const float*)d_in[0];
  const float* rel = (const float*)d_in[1];
  const float* Wq  = (const float*)d_in[2];
  const float* bq  = (const float*)d_in[3];
  const float* Wk  = (const float*)d_in[4];
  const float* bk  = (const float*)d_in[5];
  const float* Wv  = (const float*)d_in[6];
  const float* bv  = (const float*)d_in[7];
  const float* Wo  = (const float*)d_in[8];
  const float* bo  = (const float*)d_in[9];
  float* out = (float*)d_out;
  float* ws  = (float*)d_ws;

  k_qkv <<<dim3(BB * NN / 8, 3), 256, 0, stream>>>(nf, Wq, bq, Wk, bk, Wv, bv, ws);
  k_attn2<<<BB * NN, 256, 0, stream>>>(rel, Wk, Wv, ws);
  k_out <<<BB * NN / 8, 256, 0, stream>>>(nf, Wo, bo, ws, out);
}

// Round 3
// 58.715 us; speedup vs baseline: 2.7661x; 1.7318x over previous
//
#include <hip/hip_runtime.h>

// GeometricAttention: B=4, N=256, FDIM=256, REL=16, H=8, D=32
//   K[b,i,j] = Kn[b,j] + rel[b,i,j] @ Wk_r          (Kn = nf@Wk_f + bk)
//   scores   = Q.Kn^T + Qr.rel^T                     (Qr = per-head Q @ Wk_r^T)
//   sum_j attn*V = attn@Vn + (attn@rel)@Wv_r         (Vn = nf@Wv_f + bv)
// Round 3: k_attn rebuilt wave-per-2-heads, all-float4 VMEM, within-wave softmax.

#define BB 4
#define NN 256
#define FD 256
#define RL 16
#define NH 8
#define HD 32

// ws layout (float offsets)
#define OFF_Q    0
#define OFF_KN   (BB*NN*FD)            // KnT: [b][f][j]
#define OFF_VN   (2*BB*NN*FD)          // Vn:  [b][j][c]
#define OFF_WV   (3*BB*NN*FD)

#define ATP 260   // at[] row pad (float4-aligned, kills phase-D bank conflicts)
#define RLP 261   // rldsT[] row pad (odd-ish stride -> conflict-free columns)

// ---------------- Kernel 1: Q / KnT / Vn projections (fused, sel = blockIdx.y)
__global__ __launch_bounds__(256) void k_qkv(
    const float* __restrict__ nf,
    const float* __restrict__ Wq, const float* __restrict__ bq,
    const float* __restrict__ Wk, const float* __restrict__ bk,
    const float* __restrict__ Wv, const float* __restrict__ bv,
    float* __restrict__ ws) {
  const int ROWS = 8;
  __shared__ float lrow[ROWS * FD];
  const int row0 = blockIdx.x * ROWS;
  const int sel  = blockIdx.y;          // 0=Q, 1=KnT, 2=Vn
  const float* W; const float* bias;
  if (sel == 0)      { W = Wq; bias = bq; }
  else if (sel == 1) { W = Wk; bias = bk; }
  else               { W = Wv; bias = bv; }
  const int tid = threadIdx.x;
  #pragma unroll
  for (int t = 0; t < ROWS; ++t)
    lrow[t * FD + tid] = nf[(row0 + t) * FD + tid];
  __syncthreads();
  float acc[ROWS];
  #pragma unroll
  for (int r = 0; r < ROWS; ++r) acc[r] = 0.f;
  #pragma unroll 4
  for (int k = 0; k < FD; ++k) {
    const float w = W[k * FD + tid];
    #pragma unroll
    for (int r = 0; r < ROWS; ++r) acc[r] += lrow[r * FD + k] * w;
  }
  const float bb = bias[tid];
  if (sel == 1) {
    const int b2 = row0 >> 8, i0 = row0 & 255;
    float* kout = ws + OFF_KN + b2 * (FD * NN) + tid * NN + i0;
    float4 v0 = make_float4(acc[0] + bb, acc[1] + bb, acc[2] + bb, acc[3] + bb);
    float4 v1 = make_float4(acc[4] + bb, acc[5] + bb, acc[6] + bb, acc[7] + bb);
    ((float4*)kout)[0] = v0;
    ((float4*)kout)[1] = v1;
  } else {
    float* outp = ws + (sel == 0 ? OFF_Q : OFF_VN);
    #pragma unroll
    for (int r = 0; r < ROWS; ++r)
      outp[(row0 + r) * FD + tid] = acc[r] + bb;
  }
}

// ---------------- Kernel 2 (fused): qr + scores + softmax + arel + wv
// Wave w owns heads {2w, 2w+1}; softmax is within-wave (no cross-wave reduce).
__global__ __launch_bounds__(256, 4) void k_attn3(
    const float* __restrict__ rel,
    const float* __restrict__ Wk,
    const float* __restrict__ Wv,
    float* __restrict__ ws) {
  const float* Q   = ws + OFF_Q;
  const float* KnT = ws + OFF_KN;
  const float* Vn  = ws + OFF_VN;
  float* wv = ws + OFF_WV;

  // XCD-chunked swizzle: 1024 blocks on 8 XCDs -> contiguous 128-block chunks
  const int bid = (blockIdx.x & 7) * 128 + (blockIdx.x >> 3);
  const int b = bid >> 8;
  const int i = bid & 255;
  const int tid = threadIdx.x;
  const int l = tid & 63, w = tid >> 6;

  __shared__ float q[FD];            // scaled Q row
  __shared__ float qrs[NH * RL];     // per-head rel projection of q (scaled)
  __shared__ float rldsT[RL * RLP];  // rel transposed: [r][j]
  __shared__ float at[NH * ATP];     // scores -> probs, padded rows
  __shared__ float ar[NH * RL];      // attn @ rel
  __shared__ float part[4 * FD];     // phase-D partials

  const float scale = 0.17677669529663687f;  // 1/sqrt(32)
  q[tid] = Q[(b * NN + i) * FD + tid] * scale;

  // stage rel transposed; wave r4 handles rel channels 4*r4..4*r4+3
  {
    const float4* rp = (const float4*)(rel + ((size_t)(b * NN + i)) * (NN * RL));
    const int r4 = w;
    #pragma unroll
    for (int m = 0; m < 4; ++m) {
      const int j = l + 64 * m;
      float4 v = rp[j * 4 + r4];
      rldsT[(4 * r4 + 0) * RLP + j] = v.x;
      rldsT[(4 * r4 + 1) * RLP + j] = v.y;
      rldsT[(4 * r4 + 2) * RLP + j] = v.z;
      rldsT[(4 * r4 + 3) * RLP + j] = v.w;
    }
  }
  __syncthreads();   // rldsT visible to all waves (q/qrs/at stay within-wave)

  // per-wave qr for its two heads (lanes 0..31); q already scaled
  if (l < 32) {
    const int h = 2 * w + (l >> 4), r = l & 15;
    const float* wrow = Wk + (FD + r) * FD + h * HD;
    float a = 0.f;
    #pragma unroll
    for (int d = 0; d < HD; ++d) a += q[h * HD + d] * wrow[d];
    qrs[h * RL + r] = a;
  }

  // ---- phase A: qk scores for heads {2w,2w+1}, j = 4l..4l+3 (float4 KnT)
  {
    float4 s0 = make_float4(0.f, 0.f, 0.f, 0.f);
    float4 s1 = make_float4(0.f, 0.f, 0.f, 0.f);
    const float4* kp0 = (const float4*)(KnT + b * FD * NN + (2 * w) * HD * NN) + l;
    const float4* kp1 = kp0 + HD * (NN / 4);
    const float* q0 = q + 2 * w * HD;
    #pragma unroll 4
    for (int d = 0; d < HD; ++d) {
      float4 k0 = kp0[d * (NN / 4)];
      float qa = q0[d];
      s0.x += qa * k0.x; s0.y += qa * k0.y; s0.z += qa * k0.z; s0.w += qa * k0.w;
      float4 k1 = kp1[d * (NN / 4)];
      float qb = q0[HD + d];
      s1.x += qb * k1.x; s1.y += qb * k1.y; s1.z += qb * k1.z; s1.w += qb * k1.w;
    }
    ((float4*)(at + (2 * w) * ATP))[l]     = s0;
    ((float4*)(at + (2 * w + 1) * ATP))[l] = s1;
  }

  // ---- phase B: + rel-term, softmax (within-wave, j = l + 64m)
  float p[2][4];
  #pragma unroll
  for (int m = 0; m < 4; ++m) {
    const int j = l + 64 * m;
    float rv[RL];
    #pragma unroll
    for (int r = 0; r < RL; ++r) rv[r] = rldsT[r * RLP + j];
    #pragma unroll
    for (int hh = 0; hh < 2; ++hh) {
      const int h = 2 * w + hh;
      float s = at[h * ATP + j];
      #pragma unroll
      for (int r = 0; r < RL; ++r) s += qrs[h * RL + r] * rv[r];
      p[hh][m] = s;
    }
  }
  #pragma unroll
  for (int hh = 0; hh < 2; ++hh) {
    float v = fmaxf(fmaxf(p[hh][0], p[hh][1]), fmaxf(p[hh][2], p[hh][3]));
    #pragma unroll
    for (int off = 32; off; off >>= 1) v = fmaxf(v, __shfl_xor(v, off));
    float s = 0.f;
    #pragma unroll
    for (int m = 0; m < 4; ++m) { p[hh][m] = __expf(p[hh][m] - v); s += p[hh][m]; }
    #pragma unroll
    for (int off = 32; off; off >>= 1) s += __shfl_xor(s, off);
    const float rec = 1.f / s;
    #pragma unroll
    for (int m = 0; m < 4; ++m)
      at[(2 * w + hh) * ATP + l + 64 * m] = p[hh][m] * rec;
  }

  // ---- phase C: ar[h][r] = sum_j at[h][j] * rldsT[r][j]  (within-wave)
  {
    const int r = l & 15, sel = l >> 4;
    const int h = 2 * w + (sel & 1);
    const int jb = (sel >> 1) * 128;
    const float* atp = at + h * ATP + jb;
    const float* rlp = rldsT + r * RLP + jb;
    float a = 0.f;
    #pragma unroll 4
    for (int jj = 0; jj < 128; ++jj) a += atp[jj] * rlp[jj];
    a += __shfl_xor(a, 32);
    if (l < 32) ar[32 * w + l] = a;   // == ar[h*16 + r]
  }
  __syncthreads();   // all heads' probs + ar visible

  // ---- phase D: wv[c] = sum_j at[h][j]*Vn[j][c]  (float4 Vn, c = 4l..4l+3)
  {
    const int h = l >> 3;                       // (4l) >> 5
    const float4* vp = (const float4*)(Vn + b * NN * FD) + l;
    const float* ap = at + h * ATP + 64 * w;
    float4 acc = make_float4(0.f, 0.f, 0.f, 0.f);
    #pragma unroll 4
    for (int jj = 0; jj < 64; ++jj) {
      float4 v = vp[(64 * w + jj) * (FD / 4)];
      float a = ap[jj];
      acc.x += a * v.x; acc.y += a * v.y; acc.z += a * v.z; acc.w += a * v.w;
    }
    ((float4*)part)[w * 64 + l] = acc;
  }
  __syncthreads();
  {
    const int c = tid, h = c >> 5;
    float s = part[c] + part[FD + c] + part[2 * FD + c] + part[3 * FD + c];
    #pragma unroll
    for (int r = 0; r < RL; ++r) s += ar[h * RL + r] * Wv[(FD + r) * FD + c];
    wv[(b * NN + i) * FD + c] = s;
  }
}

// ---------------- Kernel 3: out = nf + wv @ Wo + bo
__global__ __launch_bounds__(256) void k_out(const float* __restrict__ nf,
                                             const float* __restrict__ Wo,
                                             const float* __restrict__ bo,
                                             const float* __restrict__ ws,
                                             float* __restrict__ out) {
  const int ROWS = 8;
  const float* wv = ws + OFF_WV;
  __shared__ float lrow[ROWS * FD];
  const int row0 = blockIdx.x * ROWS;
  const int tid = threadIdx.x;
  #pragma unroll
  for (int t = 0; t < ROWS; ++t)
    lrow[t * FD + tid] = wv[(row0 + t) * FD + tid];
  __syncthreads();
  float acc[ROWS];
  #pragma unroll
  for (int r = 0; r < ROWS; ++r) acc[r] = 0.f;
  #pragma unroll 4
  for (int k = 0; k < FD; ++k) {
    const float w = Wo[k * FD + tid];
    #pragma unroll
    for (int r = 0; r < ROWS; ++r) acc[r] += lrow[r * FD + k] * w;
  }
  const float bb = bo[tid];
  #pragma unroll
  for (int r = 0; r < ROWS; ++r)
    out[(row0 + r) * FD + tid] = nf[(row0 + r) * FD + tid] + acc[r] + bb;
}

extern "C" void kernel_launch(void* const* d_in, const int* in_sizes, int n_in,
                              void* d_out, int out_size, void* d_ws, size_t ws_size,
                              hipStream_t stream) {
  const float* nf  = (const float*)d_in[0];
  const float* rel = (const float*)d_in[1];
  const float* Wq  = (const float*)d_in[2];
  const float* bq  = (const float*)d_in[3];
  const float* Wk  = (const float*)d_in[4];
  const float* bk  = (const float*)d_in[5];
  const float* Wv  = (const float*)d_in[6];
  const float* bv  = (const float*)d_in[7];
  const float* Wo  = (const float*)d_in[8];
  const float* bo  = (const float*)d_in[9];
  float* out = (float*)d_out;
  float* ws  = (float*)d_ws;

  k_qkv  <<<dim3(BB * NN / 8, 3), 256, 0, stream>>>(nf, Wq, bq, Wk, bk, Wv, bv, ws);
  k_attn3<<<BB * NN, 256, 0, stream>>>(rel, Wk, Wv, ws);
  k_out  <<<BB * NN / 8, 256, 0, stream>>>(nf, Wo, bo, ws, out);
}

// Round 4
// 52.038 us; speedup vs baseline: 3.1209x; 1.1283x over previous
//
#include <hip/hip_runtime.h>

// GeometricAttention: B=4, N=256, FDIM=256, REL=16, H=8, D=32
//   K[b,i,j] = Kn[b,j] + rel[b,i,j] @ Wk_r          (Kn = nf@Wk_f + bk)
//   scores   = Q.Kn^T + Qr.rel^T                     (Qr = per-head Q @ Wk_r^T)
//   sum_j attn*V = attn@Vn + (attn@rel)@Wv_r         (Vn = nf@Wv_f + bv)
// Round 4: KnT/Vn stored bf16 (half L2 bytes); k_attn processes 2 Q-rows per
// block (KnT/Vn loads amortized); k_out regridded 128->512 blocks.

#define BB 4
#define NN 256
#define FD 256
#define RL 16
#define NH 8
#define HD 32

// ws layout (float offsets); KnT/Vn are bf16 (half-size regions)
#define OFF_Q    0
#define OFF_KN   (BB*NN*FD)               // ushort KnT[b][f][j]
#define OFF_VN   (OFF_KN + BB*NN*FD/2)    // ushort Vn[b][j][c]
#define OFF_WV   (OFF_VN + BB*NN*FD/2)    // float

#define ATP 260   // at[] row pad
#define RLP 261   // rldsT[] row pad (261 mod 32 = 5 -> 16 r-lanes conflict-free)

static __device__ __forceinline__ unsigned short f2bf(float x) {
  unsigned int u = __float_as_uint(x);
  unsigned int r = (u + 0x7fffu + ((u >> 16) & 1u)) >> 16;   // RNE
  return (unsigned short)r;
}
static __device__ __forceinline__ float bf2f(unsigned short h) {
  return __uint_as_float(((unsigned int)h) << 16);
}
static __device__ __forceinline__ float4 bf4(ushort4 u) {
  return make_float4(bf2f(u.x), bf2f(u.y), bf2f(u.z), bf2f(u.w));
}

// ---------------- Kernel 1: Q(fp32) / KnT(bf16,transposed) / Vn(bf16)
__global__ __launch_bounds__(256) void k_qkv(
    const float* __restrict__ nf,
    const float* __restrict__ Wq, const float* __restrict__ bq,
    const float* __restrict__ Wk, const float* __restrict__ bk,
    const float* __restrict__ Wv, const float* __restrict__ bv,
    float* __restrict__ ws) {
  const int ROWS = 8;
  __shared__ float lrow[ROWS * FD];
  const int row0 = blockIdx.x * ROWS;
  const int sel  = blockIdx.y;          // 0=Q, 1=KnT, 2=Vn
  const float* W; const float* bias;
  if (sel == 0)      { W = Wq; bias = bq; }
  else if (sel == 1) { W = Wk; bias = bk; }
  else               { W = Wv; bias = bv; }
  const int tid = threadIdx.x;
  #pragma unroll
  for (int t = 0; t < ROWS; ++t)
    lrow[t * FD + tid] = nf[(row0 + t) * FD + tid];
  __syncthreads();
  float acc[ROWS];
  #pragma unroll
  for (int r = 0; r < ROWS; ++r) acc[r] = 0.f;
  #pragma unroll 16
  for (int k = 0; k < FD; ++k) {
    const float w = W[k * FD + tid];
    #pragma unroll
    for (int r = 0; r < ROWS; ++r) acc[r] += lrow[r * FD + k] * w;
  }
  const float bb = bias[tid];
  if (sel == 1) {
    // KnT bf16 [b][f=tid][j], 8 consecutive j per lane -> two ushort4 stores
    const int b2 = row0 >> 8, i0 = row0 & 255;
    unsigned short* kout = (unsigned short*)(ws + OFF_KN) + ((size_t)b2 * FD + tid) * NN + i0;
    ushort4 v0, v1;
    v0.x = f2bf(acc[0] + bb); v0.y = f2bf(acc[1] + bb);
    v0.z = f2bf(acc[2] + bb); v0.w = f2bf(acc[3] + bb);
    v1.x = f2bf(acc[4] + bb); v1.y = f2bf(acc[5] + bb);
    v1.z = f2bf(acc[6] + bb); v1.w = f2bf(acc[7] + bb);
    ((ushort4*)kout)[0] = v0;
    ((ushort4*)kout)[1] = v1;
  } else if (sel == 2) {
    unsigned short* outp = (unsigned short*)(ws + OFF_VN);
    #pragma unroll
    for (int r = 0; r < ROWS; ++r)
      outp[(size_t)(row0 + r) * FD + tid] = f2bf(acc[r] + bb);
  } else {
    float* outp = ws + OFF_Q;
    #pragma unroll
    for (int r = 0; r < ROWS; ++r)
      outp[(row0 + r) * FD + tid] = acc[r] + bb;
  }
}

// ---------------- Kernel 2 (fused, 2 rows/block): qr+scores+softmax+arel+wv
// Wave w owns heads {2w,2w+1} for BOTH rows; softmax within-wave.
__global__ __launch_bounds__(256, 2) void k_attn4(
    const float* __restrict__ rel,
    const float* __restrict__ Wk,
    const float* __restrict__ Wv,
    float* __restrict__ ws) {
  const float* Q = ws + OFF_Q;
  const unsigned short* KnB = (const unsigned short*)(ws + OFF_KN);
  const unsigned short* VnB = (const unsigned short*)(ws + OFF_VN);
  float* wv = ws + OFF_WV;

  // XCD-chunked swizzle over 512 blocks (512 % 8 == 0 -> bijective)
  const int bid = (blockIdx.x & 7) * 64 + (blockIdx.x >> 3);
  const int b  = bid >> 7;
  const int i0 = (bid & 127) * 2;
  const int tid = threadIdx.x;
  const int l = tid & 63, w = tid >> 6;

  __shared__ float q[2][FD];           // scaled Q rows
  __shared__ float qrs[2][NH * RL];
  __shared__ float rldsT[2 * RL * RLP];
  __shared__ float at[2 * NH * ATP];
  __shared__ float ar[2][NH * RL];
  __shared__ float part[2 * 4 * FD];

  const float scale = 0.17677669529663687f;  // 1/sqrt(32)
  q[0][tid] = Q[(b * NN + i0) * FD + tid] * scale;
  q[1][tid] = Q[(b * NN + i0 + 1) * FD + tid] * scale;

  // stage rel transposed for both rows; wave w handles channels 4w..4w+3
  #pragma unroll
  for (int ii = 0; ii < 2; ++ii) {
    const float4* rp = (const float4*)(rel + ((size_t)(b * NN + i0 + ii)) * (NN * RL));
    #pragma unroll
    for (int m = 0; m < 4; ++m) {
      const int j = l + 64 * m;
      float4 v = rp[j * 4 + w];
      rldsT[(ii * RL + 4 * w + 0) * RLP + j] = v.x;
      rldsT[(ii * RL + 4 * w + 1) * RLP + j] = v.y;
      rldsT[(ii * RL + 4 * w + 2) * RLP + j] = v.z;
      rldsT[(ii * RL + 4 * w + 3) * RLP + j] = v.w;
    }
  }

  // qr for wave's two heads, both rows (all 64 lanes; wave-local LDS)
  {
    const int ii = l >> 5, hh = (l >> 4) & 1, r = l & 15;
    const int h = 2 * w + hh;
    const float* wrow = Wk + (FD + r) * FD + h * HD;
    const float* qq = &q[ii][h * HD];
    float a = 0.f;
    #pragma unroll
    for (int d = 0; d < HD; ++d) a += qq[d] * wrow[d];
    qrs[ii][h * RL + r] = a;
  }
  __syncthreads();   // rldsT visible to all waves

  // ---- phase A: qk scores, j = 4l..4l+3, bf16 KnT (8B loads)
  {
    float4 s00 = make_float4(0,0,0,0), s01 = make_float4(0,0,0,0);
    float4 s10 = make_float4(0,0,0,0), s11 = make_float4(0,0,0,0);
    const ushort4* kp = (const ushort4*)(KnB + ((size_t)b * FD + 64 * w) * NN) + l;
    const float* q0 = &q[0][64 * w];
    const float* q1 = &q[1][64 * w];
    #pragma unroll 8
    for (int d = 0; d < HD; ++d) {
      float4 k0 = bf4(kp[d * (NN / 4)]);          // head 2w
      float4 k1 = bf4(kp[(HD + d) * (NN / 4)]);   // head 2w+1
      float a0 = q0[d], a1 = q0[HD + d], b0 = q1[d], b1 = q1[HD + d];
      s00.x += a0*k0.x; s00.y += a0*k0.y; s00.z += a0*k0.z; s00.w += a0*k0.w;
      s10.x += b0*k0.x; s10.y += b0*k0.y; s10.z += b0*k0.z; s10.w += b0*k0.w;
      s01.x += a1*k1.x; s01.y += a1*k1.y; s01.z += a1*k1.z; s01.w += a1*k1.w;
      s11.x += b1*k1.x; s11.y += b1*k1.y; s11.z += b1*k1.z; s11.w += b1*k1.w;
    }
    ((float4*)(at + (2 * w) * ATP))[l]           = s00;
    ((float4*)(at + (2 * w + 1) * ATP))[l]       = s01;
    ((float4*)(at + (8 + 2 * w) * ATP))[l]       = s10;
    ((float4*)(at + (8 + 2 * w + 1) * ATP))[l]   = s11;
  }

  // ---- phase B: + rel-term, within-wave softmax (j = l + 64m)
  float pr[2][2][4];
  #pragma unroll
  for (int ii = 0; ii < 2; ++ii) {
    #pragma unroll
    for (int m = 0; m < 4; ++m) {
      const int j = l + 64 * m;
      float rv[RL];
      #pragma unroll
      for (int r = 0; r < RL; ++r) rv[r] = rldsT[(ii * RL + r) * RLP + j];
      #pragma unroll
      for (int hh = 0; hh < 2; ++hh) {
        const int h = 2 * w + hh;
        float s = at[(ii * NH + h) * ATP + j];
        #pragma unroll
        for (int r = 0; r < RL; ++r) s += qrs[ii][h * RL + r] * rv[r];
        pr[ii][hh][m] = s;
      }
    }
  }
  #pragma unroll
  for (int ii = 0; ii < 2; ++ii) {
    #pragma unroll
    for (int hh = 0; hh < 2; ++hh) {
      float v = fmaxf(fmaxf(pr[ii][hh][0], pr[ii][hh][1]),
                      fmaxf(pr[ii][hh][2], pr[ii][hh][3]));
      #pragma unroll
      for (int off = 32; off; off >>= 1) v = fmaxf(v, __shfl_xor(v, off));
      float s = 0.f;
      #pragma unroll
      for (int m = 0; m < 4; ++m) { pr[ii][hh][m] = __expf(pr[ii][hh][m] - v); s += pr[ii][hh][m]; }
      #pragma unroll
      for (int off = 32; off; off >>= 1) s += __shfl_xor(s, off);
      const float rec = 1.f / s;
      #pragma unroll
      for (int m = 0; m < 4; ++m)
        at[(ii * NH + 2 * w + hh) * ATP + l + 64 * m] = pr[ii][hh][m] * rec;
    }
  }

  // ---- phase C: ar[ii][h][r] = sum_j at*relT (within-wave)
  #pragma unroll
  for (int ii = 0; ii < 2; ++ii) {
    const int r = l & 15, sel = l >> 4;
    const int h = 2 * w + (sel & 1);
    const int jb = (sel >> 1) * 128;
    const float* atp = at + (ii * NH + h) * ATP + jb;
    const float* rlp = rldsT + (ii * RL + r) * RLP + jb;
    float a = 0.f;
    #pragma unroll 4
    for (int jj = 0; jj < 128; ++jj) a += atp[jj] * rlp[jj];
    a += __shfl_xor(a, 32);
    if (l < 32) ar[ii][32 * w + l] = a;   // == ar[ii][h*16 + r]
  }
  __syncthreads();   // all heads' probs + ar visible

  // ---- phase D: partial wv, c = 4l..4l+3, bf16 Vn (8B loads), both rows
  {
    const int h = l >> 3;                    // (4l) >> 5
    const ushort4* vp = (const ushort4*)(VnB + (size_t)b * NN * FD) + l;
    const float* ap0 = at + h * ATP + 64 * w;
    const float* ap1 = at + (NH + h) * ATP + 64 * w;
    float4 a0 = make_float4(0,0,0,0), a1 = make_float4(0,0,0,0);
    #pragma unroll 4
    for (int jj = 0; jj < 64; ++jj) {
      float4 v = bf4(vp[(64 * w + jj) * (FD / 4)]);
      float p0 = ap0[jj], p1 = ap1[jj];
      a0.x += p0*v.x; a0.y += p0*v.y; a0.z += p0*v.z; a0.w += p0*v.w;
      a1.x += p1*v.x; a1.y += p1*v.y; a1.z += p1*v.z; a1.w += p1*v.w;
    }
    ((float4*)part)[w * 64 + l]       = a0;
    ((float4*)part)[(4 + w) * 64 + l] = a1;
  }
  __syncthreads();

  // ---- phase E: reduce partials + Wv_r term, write both rows
  {
    const int c = tid, h = c >> 5;
    float s0 = part[c] + part[FD + c] + part[2*FD + c] + part[3*FD + c];
    float s1 = part[4*FD + c] + part[5*FD + c] + part[6*FD + c] + part[7*FD + c];
    #pragma unroll
    for (int r = 0; r < RL; ++r) {
      const float wvr = Wv[(FD + r) * FD + c];
      s0 += ar[0][h * RL + r] * wvr;
      s1 += ar[1][h * RL + r] * wvr;
    }
    wv[(b * NN + i0) * FD + c]     = s0;
    wv[(b * NN + i0 + 1) * FD + c] = s1;
  }
}

// ---------------- Kernel 3: out = nf + wv @ Wo + bo  (512 blocks)
__global__ __launch_bounds__(256) void k_out(const float* __restrict__ nf,
                                             const float* __restrict__ Wo,
                                             const float* __restrict__ bo,
                                             const float* __restrict__ ws,
                                             float* __restrict__ out) {
  const int ROWS = 2;
  const float* wv = ws + OFF_WV;
  __shared__ float lrow[ROWS * FD];
  const int row0 = blockIdx.x * ROWS;
  const int tid = threadIdx.x;
  #pragma unroll
  for (int t = 0; t < ROWS; ++t)
    lrow[t * FD + tid] = wv[(row0 + t) * FD + tid];
  __syncthreads();
  float acc[ROWS];
  #pragma unroll
  for (int r = 0; r < ROWS; ++r) acc[r] = 0.f;
  #pragma unroll 16
  for (int k = 0; k < FD; ++k) {
    const float w = Wo[k * FD + tid];
    #pragma unroll
    for (int r = 0; r < ROWS; ++r) acc[r] += lrow[r * FD + k] * w;
  }
  const float bb = bo[tid];
  #pragma unroll
  for (int r = 0; r < ROWS; ++r)
    out[(row0 + r) * FD + tid] = nf[(row0 + r) * FD + tid] + acc[r] + bb;
}

extern "C" void kernel_launch(void* const* d_in, const int* in_sizes, int n_in,
                              void* d_out, int out_size, void* d_ws, size_t ws_size,
                              hipStream_t stream) {
  const float* nf  = (const float*)d_in[0];
  const float* rel = (const float*)d_in[1];
  const float* Wq  = (const float*)d_in[2];
  const float* bq  = (const float*)d_in[3];
  const float* Wk  = (const float*)d_in[4];
  const float* bk  = (const float*)d_in[5];
  const float* Wv  = (const float*)d_in[6];
  const float* bv  = (const float*)d_in[7];
  const float* Wo  = (const float*)d_in[8];
  const float* bo  = (const float*)d_in[9];
  float* out = (float*)d_out;
  float* ws  = (float*)d_ws;

  k_qkv  <<<dim3(BB * NN / 8, 3), 256, 0, stream>>>(nf, Wq, bq, Wk, bk, Wv, bv, ws);
  k_attn4<<<BB * NN / 2, 256, 0, stream>>>(rel, Wk, Wv, ws);
  k_out  <<<BB * NN / 2, 256, 0, stream>>>(nf, Wo, bo, ws, out);
}

// Round 5
// 41.613 us; speedup vs baseline: 3.9028x; 1.2505x over previous
//
#include <hip/hip_runtime.h>

// GeometricAttention: B=4, N=256, FDIM=256, REL=16, H=8, D=32
//   K[b,i,j] = Kn[b,j] + rel[b,i,j] @ Wk_r          (Kn = nf@Wk_f + bk)
//   scores   = Q.Kn^T + Qr.rel^T                     (Qr = per-head Q @ Wk_r^T)
//   sum_j attn*V = attn@Vn + (attn@rel)@Wv_r         (Vn = nf@Wv_f + bv)
// Round 5: 2 kernels. k_out fused into k_attn (wv never leaves the block);
// k_qkv inner loop = broadcast b128 reads; attn keeps scores in registers.

#define BB 4
#define NN 256
#define FD 256
#define RL 16
#define NH 8
#define HD 32

// ws layout (float offsets); KnT/Vn are bf16
#define OFF_Q    0
#define OFF_KN   (BB*NN*FD)               // ushort KnT[b][f][j]
#define OFF_VN   (OFF_KN + BB*NN*FD/2)    // ushort Vn[b][j][c]

#define ATP 260   // at[] row pad (words, x4-aligned)
#define RLP 20    // rlds row pad (words, x4-aligned, non-pow2 banking)

static __device__ __forceinline__ unsigned short f2bf(float x) {
  unsigned int u = __float_as_uint(x);
  unsigned int r = (u + 0x7fffu + ((u >> 16) & 1u)) >> 16;   // RNE
  return (unsigned short)r;
}
static __device__ __forceinline__ float bf2f(unsigned short h) {
  return __uint_as_float(((unsigned int)h) << 16);
}
static __device__ __forceinline__ float4 bf4(ushort4 u) {
  return make_float4(bf2f(u.x), bf2f(u.y), bf2f(u.z), bf2f(u.w));
}

// ---------------- Kernel 1: Q(fp32) / KnT(bf16,transposed) / Vn(bf16)
__global__ __launch_bounds__(256) void k_qkv5(
    const float* __restrict__ nf,
    const float* __restrict__ Wq, const float* __restrict__ bq,
    const float* __restrict__ Wk, const float* __restrict__ bk,
    const float* __restrict__ Wv, const float* __restrict__ bv,
    float* __restrict__ ws) {
  const int ROWS = 8;
  __shared__ float lrowT[FD][ROWS];     // [k][r] -> inner loop reads 2x b128 bcast
  const int row0 = blockIdx.x * ROWS;
  const int sel  = blockIdx.y;          // 0=Q, 1=KnT, 2=Vn
  const float* W; const float* bias;
  if (sel == 0)      { W = Wq; bias = bq; }
  else if (sel == 1) { W = Wk; bias = bk; }
  else               { W = Wv; bias = bv; }
  const int tid = threadIdx.x;
  {
    float v[ROWS];
    #pragma unroll
    for (int t = 0; t < ROWS; ++t) v[t] = nf[(row0 + t) * FD + tid];
    #pragma unroll
    for (int t = 0; t < ROWS; ++t) lrowT[tid][t] = v[t];
  }
  __syncthreads();
  float acc[ROWS];
  #pragma unroll
  for (int r = 0; r < ROWS; ++r) acc[r] = 0.f;
  #pragma unroll 8
  for (int k = 0; k < FD; ++k) {
    const float w = W[k * FD + tid];
    float4 a0 = *(const float4*)&lrowT[k][0];
    float4 a1 = *(const float4*)&lrowT[k][4];
    acc[0] += a0.x * w; acc[1] += a0.y * w; acc[2] += a0.z * w; acc[3] += a0.w * w;
    acc[4] += a1.x * w; acc[5] += a1.y * w; acc[6] += a1.z * w; acc[7] += a1.w * w;
  }
  const float bb = bias[tid];
  if (sel == 1) {
    const int b2 = row0 >> 8, i0 = row0 & 255;
    unsigned short* kout = (unsigned short*)(ws + OFF_KN) + ((size_t)b2 * FD + tid) * NN + i0;
    ushort4 v0, v1;
    v0.x = f2bf(acc[0] + bb); v0.y = f2bf(acc[1] + bb);
    v0.z = f2bf(acc[2] + bb); v0.w = f2bf(acc[3] + bb);
    v1.x = f2bf(acc[4] + bb); v1.y = f2bf(acc[5] + bb);
    v1.z = f2bf(acc[6] + bb); v1.w = f2bf(acc[7] + bb);
    ((ushort4*)kout)[0] = v0;
    ((ushort4*)kout)[1] = v1;
  } else if (sel == 2) {
    unsigned short* outp = (unsigned short*)(ws + OFF_VN);
    #pragma unroll
    for (int r = 0; r < ROWS; ++r)
      outp[(size_t)(row0 + r) * FD + tid] = f2bf(acc[r] + bb);
  } else {
    float* outp = ws + OFF_Q;
    #pragma unroll
    for (int r = 0; r < ROWS; ++r)
      outp[(row0 + r) * FD + tid] = acc[r] + bb;
  }
}

// ---------------- Kernel 2: qr + scores + softmax + arel + wv + OUTPUT
// 2 Q-rows/block; wave w owns heads {2w,2w+1}; j = 4l..4l+3 throughout.
__global__ __launch_bounds__(256, 2) void k_attn5(
    const float* __restrict__ rel,
    const float* __restrict__ Wk,
    const float* __restrict__ Wv,
    const float* __restrict__ nf,
    const float* __restrict__ Wo,
    const float* __restrict__ bo,
    float* __restrict__ out,
    float* __restrict__ ws) {
  const float* Q = ws + OFF_Q;
  const unsigned short* KnB = (const unsigned short*)(ws + OFF_KN);
  const unsigned short* VnB = (const unsigned short*)(ws + OFF_VN);

  // XCD-chunked swizzle over 512 blocks (bijective)
  const int bid = (blockIdx.x & 7) * 64 + (blockIdx.x >> 3);
  const int b  = bid >> 7;
  const int i0 = (bid & 127) * 2;
  const int tid = threadIdx.x;
  const int l = tid & 63, w = tid >> 6;

  __shared__ float q[2][FD];           // scaled Q rows       (2 KB)
  __shared__ float qrs[2][NH * RL];    //                     (1 KB)
  __shared__ float rlds[2 * NN * RLP]; // rel rows, pad 20    (40 KB)
  __shared__ float at[2 * NH * ATP];   // attn probs          (16.6 KB)
  __shared__ float ar[2][NH * RL];     //                     (1 KB)
  __shared__ float part[8 * FD];       // phase-D partials    (8 KB)
  __shared__ float wvT[FD * 2];        // wv interleaved rows (2 KB)

  const float scale = 0.17677669529663687f;  // 1/sqrt(32)
  q[0][tid] = Q[(b * NN + i0) * FD + tid] * scale;
  q[1][tid] = Q[(b * NN + i0 + 1) * FD + tid] * scale;

  // stage rel rows (row-major, pad RLP) — pure float4 copy, no transpose
  #pragma unroll
  for (int ii = 0; ii < 2; ++ii) {
    const float4* rp = (const float4*)(rel + ((size_t)(b * NN + i0 + ii)) * (NN * RL));
    #pragma unroll
    for (int m = 0; m < 4; ++m) {
      const int idx = tid + 256 * m;           // [0,1024): j = idx>>2, quarter = idx&3
      float4 v = rp[idx];
      *(float4*)&rlds[(ii * NN + (idx >> 2)) * RLP + (idx & 3) * 4] = v;
    }
  }

  // qr for wave's two heads, both rows (wave-local: q[ii][64w..64w+63] was
  // written by this wave's threads)
  {
    const int ii = l >> 5, hh = (l >> 4) & 1, r = l & 15;
    const int h = 2 * w + hh;
    const float* wrow = Wk + (FD + r) * FD + h * HD;
    const float* qq = &q[ii][h * HD];
    float a = 0.f;
    #pragma unroll
    for (int d = 0; d < HD; ++d) a += qq[d] * wrow[d];
    qrs[ii][h * RL + r] = a;
  }
  __syncthreads();   // rlds cross-wave

  // ---- phase A: scores s[ii][hh][jj], j = 4l+jj, bf16 KnT
  float s[2][2][4];
  #pragma unroll
  for (int ii = 0; ii < 2; ++ii)
    #pragma unroll
    for (int hh = 0; hh < 2; ++hh)
      #pragma unroll
      for (int jj = 0; jj < 4; ++jj) s[ii][hh][jj] = 0.f;
  {
    const ushort4* kp = (const ushort4*)(KnB + ((size_t)b * FD + 64 * w) * NN) + l;
    #pragma unroll 2
    for (int dd = 0; dd < 8; ++dd) {
      float4 qv00 = *(const float4*)&q[0][64 * w + 4 * dd];
      float4 qv01 = *(const float4*)&q[0][64 * w + 32 + 4 * dd];
      float4 qv10 = *(const float4*)&q[1][64 * w + 4 * dd];
      float4 qv11 = *(const float4*)&q[1][64 * w + 32 + 4 * dd];
      #pragma unroll
      for (int e = 0; e < 4; ++e) {
        float4 k0 = bf4(kp[(4 * dd + e) * (NN / 4)]);        // head 2w
        float4 k1 = bf4(kp[(32 + 4 * dd + e) * (NN / 4)]);   // head 2w+1
        const float a0 = (&qv00.x)[e], a1 = (&qv01.x)[e];
        const float b0 = (&qv10.x)[e], b1 = (&qv11.x)[e];
        s[0][0][0] += a0 * k0.x; s[0][0][1] += a0 * k0.y;
        s[0][0][2] += a0 * k0.z; s[0][0][3] += a0 * k0.w;
        s[1][0][0] += b0 * k0.x; s[1][0][1] += b0 * k0.y;
        s[1][0][2] += b0 * k0.z; s[1][0][3] += b0 * k0.w;
        s[0][1][0] += a1 * k1.x; s[0][1][1] += a1 * k1.y;
        s[0][1][2] += a1 * k1.z; s[0][1][3] += a1 * k1.w;
        s[1][1][0] += b1 * k1.x; s[1][1][1] += b1 * k1.y;
        s[1][1][2] += b1 * k1.z; s[1][1][3] += b1 * k1.w;
      }
    }
  }

  // ---- rel-term: s += qr . rel[j], float4 reads of rlds + qrs
  #pragma unroll
  for (int ii = 0; ii < 2; ++ii) {
    float4 qa0 = *(const float4*)&qrs[ii][(2 * w) * RL + 0];
    float4 qa1 = *(const float4*)&qrs[ii][(2 * w) * RL + 4];
    float4 qa2 = *(const float4*)&qrs[ii][(2 * w) * RL + 8];
    float4 qa3 = *(const float4*)&qrs[ii][(2 * w) * RL + 12];
    float4 qb0 = *(const float4*)&qrs[ii][(2 * w + 1) * RL + 0];
    float4 qb1 = *(const float4*)&qrs[ii][(2 * w + 1) * RL + 4];
    float4 qb2 = *(const float4*)&qrs[ii][(2 * w + 1) * RL + 8];
    float4 qb3 = *(const float4*)&qrs[ii][(2 * w + 1) * RL + 12];
    #pragma unroll
    for (int jj = 0; jj < 4; ++jj) {
      const float* rv = &rlds[(ii * NN + 4 * l + jj) * RLP];
      float4 r0 = *(const float4*)&rv[0];
      float4 r1 = *(const float4*)&rv[4];
      float4 r2 = *(const float4*)&rv[8];
      float4 r3 = *(const float4*)&rv[12];
      s[ii][0][jj] += qa0.x*r0.x + qa0.y*r0.y + qa0.z*r0.z + qa0.w*r0.w
                    + qa1.x*r1.x + qa1.y*r1.y + qa1.z*r1.z + qa1.w*r1.w
                    + qa2.x*r2.x + qa2.y*r2.y + qa2.z*r2.z + qa2.w*r2.w
                    + qa3.x*r3.x + qa3.y*r3.y + qa3.z*r3.z + qa3.w*r3.w;
      s[ii][1][jj] += qb0.x*r0.x + qb0.y*r0.y + qb0.z*r0.z + qb0.w*r0.w
                    + qb1.x*r1.x + qb1.y*r1.y + qb1.z*r1.z + qb1.w*r1.w
                    + qb2.x*r2.x + qb2.y*r2.y + qb2.z*r2.z + qb2.w*r2.w
                    + qb3.x*r3.x + qb3.y*r3.y + qb3.z*r3.z + qb3.w*r3.w;
    }
  }

  // ---- phase B: within-wave softmax over all 256 j (lane covers 4l..4l+3)
  #pragma unroll
  for (int ii = 0; ii < 2; ++ii) {
    #pragma unroll
    for (int hh = 0; hh < 2; ++hh) {
      float v = fmaxf(fmaxf(s[ii][hh][0], s[ii][hh][1]),
                      fmaxf(s[ii][hh][2], s[ii][hh][3]));
      #pragma unroll
      for (int off = 32; off; off >>= 1) v = fmaxf(v, __shfl_xor(v, off));
      float4 p;
      p.x = __expf(s[ii][hh][0] - v); p.y = __expf(s[ii][hh][1] - v);
      p.z = __expf(s[ii][hh][2] - v); p.w = __expf(s[ii][hh][3] - v);
      float sum = p.x + p.y + p.z + p.w;
      #pragma unroll
      for (int off = 32; off; off >>= 1) sum += __shfl_xor(sum, off);
      const float rec = 1.f / sum;
      p.x *= rec; p.y *= rec; p.z *= rec; p.w *= rec;
      *(float4*)&at[(ii * NH + 2 * w + hh) * ATP + 4 * l] = p;
    }
  }

  // ---- phase C: ar[ii][h][r] = sum_j at[h][j] * rel[j][r] (wave-local rows)
  #pragma unroll
  for (int ii = 0; ii < 2; ++ii) {
    const int r = l & 15, sl = l >> 4;
    const int h = 2 * w + (sl & 1);
    const int jb = (sl >> 1) * 128;
    const float* atp = at + (ii * NH + h) * ATP + jb;
    const float* rlp = rlds + (ii * NN + jb) * RLP + r;
    float a = 0.f;
    #pragma unroll 4
    for (int jj = 0; jj < 128; ++jj) a += atp[jj] * rlp[jj * RLP];
    a += __shfl_xor(a, 32);
    if (l < 32) ar[ii][32 * w + l] = a;   // == ar[ii][h*16 + r]
  }
  __syncthreads();   // at (all heads) + ar cross-wave

  // ---- phase D: partial wv over j-range [64w,64w+64), c = 4l..4l+3
  {
    const int h = l >> 3;
    const ushort4* vp = (const ushort4*)(VnB + (size_t)b * NN * FD) + l;
    const float* ap0 = at + h * ATP + 64 * w;
    const float* ap1 = at + (NH + h) * ATP + 64 * w;
    float4 a0 = make_float4(0,0,0,0), a1 = make_float4(0,0,0,0);
    #pragma unroll 4
    for (int jj = 0; jj < 64; ++jj) {
      float4 v = bf4(vp[(64 * w + jj) * (FD / 4)]);
      float p0 = ap0[jj], p1 = ap1[jj];
      a0.x += p0*v.x; a0.y += p0*v.y; a0.z += p0*v.z; a0.w += p0*v.w;
      a1.x += p1*v.x; a1.y += p1*v.y; a1.z += p1*v.z; a1.w += p1*v.w;
    }
    ((float4*)part)[w * 64 + l]       = a0;
    ((float4*)part)[(4 + w) * 64 + l] = a1;
  }
  __syncthreads();

  // ---- phase E: reduce partials + Wv_r term -> wvT[k][ii] in LDS
  {
    const int c = tid, h2 = c >> 5;
    float s0 = part[c] + part[FD + c] + part[2*FD + c] + part[3*FD + c];
    float s1 = part[4*FD + c] + part[5*FD + c] + part[6*FD + c] + part[7*FD + c];
    #pragma unroll
    for (int r = 0; r < RL; ++r) {
      const float wvr = Wv[(FD + r) * FD + c];
      s0 += ar[0][h2 * RL + r] * wvr;
      s1 += ar[1][h2 * RL + r] * wvr;
    }
    *(float2*)&wvT[2 * c] = make_float2(s0, s1);
  }
  __syncthreads();

  // ---- phase F: out[i0+ii][c] = nf + wv[ii] @ Wo + bo (b128 bcast + Wo dwords)
  {
    const int c = tid;
    float acc0 = 0.f, acc1 = 0.f;
    #pragma unroll 4
    for (int k4 = 0; k4 < FD / 4; ++k4) {
      float4 wa = *(const float4*)&wvT[8 * k4];       // k=4k4, 4k4+1 (rows 0,1)
      float4 wb = *(const float4*)&wvT[8 * k4 + 4];   // k=4k4+2, 4k4+3
      float w0 = Wo[(4 * k4 + 0) * FD + c];
      float w1 = Wo[(4 * k4 + 1) * FD + c];
      float w2 = Wo[(4 * k4 + 2) * FD + c];
      float w3 = Wo[(4 * k4 + 3) * FD + c];
      acc0 += wa.x * w0 + wa.z * w1 + wb.x * w2 + wb.z * w3;
      acc1 += wa.y * w0 + wa.w * w1 + wb.y * w2 + wb.w * w3;
    }
    const float bb = bo[c];
    out[(b * NN + i0) * FD + c]     = nf[(b * NN + i0) * FD + c]     + acc0 + bb;
    out[(b * NN + i0 + 1) * FD + c] = nf[(b * NN + i0 + 1) * FD + c] + acc1 + bb;
  }
}

extern "C" void kernel_launch(void* const* d_in, const int* in_sizes, int n_in,
                              void* d_out, int out_size, void* d_ws, size_t ws_size,
                              hipStream_t stream) {
  const float* nf  = (const float*)d_in[0];
  const float* rel = (const float*)d_in[1];
  const float* Wq  = (const float*)d_in[2];
  const float* bq  = (const float*)d_in[3];
  const float* Wk  = (const float*)d_in[4];
  const float* bk  = (const float*)d_in[5];
  const float* Wv  = (const float*)d_in[6];
  const float* bv  = (const float*)d_in[7];
  const float* Wo  = (const float*)d_in[8];
  const float* bo  = (const float*)d_in[9];
  float* out = (float*)d_out;
  float* ws  = (float*)d_ws;

  k_qkv5 <<<dim3(BB * NN / 8, 3), 256, 0, stream>>>(nf, Wq, bq, Wk, bk, Wv, bv, ws);
  k_attn5<<<BB * NN / 2, 256, 0, stream>>>(rel, Wk, Wv, nf, Wo, bo, out, ws);
}